// Round 2
// baseline (24994.061 us; speedup 1.0000x reference)
//
#include <hip/hip_runtime.h>
#include <stdint.h>

typedef _Float16 f16;
typedef _Float16 half8 __attribute__((ext_vector_type(8)));
typedef _Float16 half4 __attribute__((ext_vector_type(4)));
typedef float float4v __attribute__((ext_vector_type(4)));
typedef float float2v __attribute__((ext_vector_type(2)));
typedef unsigned int u32;

#define MFMA16(A, B, C) __builtin_amdgcn_mfma_f32_16x16x32_f16((A), (B), (C), 0, 0, 0)

static constexpr int Bsz = 512, Tsz = 512, Fsz = 128, Lsz = 512;
static constexpr int NPACK = 2176;  // [r|z|in|hn] (4*512) + y (128)
static constexpr float LO_S = 2048.0f, LO_R = 1.0f / 2048.0f;

// ws layout (bytes)
static constexpr size_t WSZ_FRAG  = (size_t)(NPACK / 16) * 16 * 64 * 8 * 2;  // 2,228,224
static constexpr size_t OFF_WHI   = 0;
static constexpr size_t OFF_WLO   = OFF_WHI + WSZ_FRAG;
static constexpr size_t OFF_BIAS  = OFF_WLO + WSZ_FRAG;                  // 4,456,448
static constexpr size_t OFF_HHI   = OFF_BIAS + 16384;                    // 2 bufs x 512x512 f16
static constexpr size_t OFF_HLO   = OFF_HHI + (size_t)2 * Bsz * Lsz * 2;
static constexpr size_t OFF_FLAGS = OFF_HLO + (size_t)2 * Bsz * Lsz * 2; // 256*32 ints

// LDS layout (bytes); dynamic, 152,064 total
static constexpr int LDS_HI = 0;        // f16 [32][512] swizzled
static constexpr int LDS_LO = 32768;    // f16 [32][512] swizzled
static constexpr int LDS_EX = 65536;    // f32 [4t][4w][32col][38]
static constexpr int LDS_YP = 143360;   // f32 [4w][32row][17]
static constexpr int LDS_TOT = 152064;
static constexpr int EXS = 38;

// XOR swizzle of a column within a 512-col row (granule = 8 f16 = 16 B)
__device__ __host__ __forceinline__ int swz(int c, int r) {
  return (((c >> 3) ^ (r & 7)) << 3) | (c & 7);
}

__device__ __forceinline__ void async16(const void* g, void* l) {
  __builtin_amdgcn_global_load_lds((const __attribute__((address_space(1))) u32*)g,
                                   (__attribute__((address_space(3))) u32*)l, 16, 0, 0);
}

__device__ __forceinline__ float sigm(float x) { return 1.0f / (1.0f + __expf(-x)); }
__device__ __forceinline__ float tanh_(float x) { return 1.0f - 2.0f / (__expf(2.0f * x) + 1.0f); }

// ---------------- prep kernel 1: fold + split + fragment-pack weights ----------------
// packed col c: [0,1024): r/z combined = M[l][c] + Whh[c][l]
//               [1024,1536): i_n       = M[l][c]
//               [1536,2048): h_n       = Whh[c-512][l]
//               [2048,2176): y         = Wd[c-2048][l]
// where M[l][j] = sum_f Wd[f][l] * Wih[j][f]  (dense layer folded into input weights)
__global__ void k_pack(const float* __restrict__ Wih, const float* __restrict__ Whh,
                       const float* __restrict__ Wd, f16* __restrict__ whiF,
                       f16* __restrict__ wloF) {
  const int c = blockIdx.y;                      // 0..2175 (uniform per block)
  const int l = blockIdx.x * 256 + threadIdx.x;  // 0..511 (contraction index)
  float v;
  if (c < 1536) {
    const float* wih = Wih + c * 128;
    float acc = 0.f;
#pragma unroll 8
    for (int f = 0; f < 128; ++f) acc = fmaf(Wd[f * 512 + l], wih[f], acc);
    v = acc;
    if (c < 1024) v += Whh[c * 512 + l];
  } else if (c < 2048) {
    v = Whh[(c - 512) * 512 + l];
  } else {
    v = Wd[(c - 2048) * 512 + l];
  }
  f16 hi = (f16)v;
  f16 lo = (f16)((v - (float)hi) * LO_S);  // scaled: raw residual is fp16-subnormal
  // B-fragment layout for mfma 16x16x32: lane=q*16+n holds B[k=32*ks+8*q+j][n]
  const int chunk = c >> 4, ks = l >> 5, q = (l >> 3) & 3, j = l & 7, n = c & 15;
  const size_t idx = (((size_t)(chunk * 16 + ks)) * 64 + q * 16 + n) * 8 + j;
  whiF[idx] = hi;
  wloF[idx] = lo;
}

// ---------------- prep kernel 2: h planes (buffer 0), biases, flags ----------------
__global__ void k_init(const float* __restrict__ h0, const float* __restrict__ Wih,
                       const float* __restrict__ bih, const float* __restrict__ bhh,
                       const float* __restrict__ bd, f16* __restrict__ hhi,
                       f16* __restrict__ hlo, float* __restrict__ biasP,
                       int* __restrict__ flags) {
  const int t = blockIdx.x * 256 + threadIdx.x;
  if (t < Bsz * Lsz) {
    const int row = t >> 9, col = t & 511;
    float v = h0[t];
    f16 hi = (f16)v;
    f16 lo = (f16)((v - (float)hi) * LO_S);
    const int cp = swz(col, row);
    hhi[row * 512 + cp] = hi;  // buffer 0
    hlo[row * 512 + cp] = lo;
  }
  if (t < NPACK) {
    float v;
    if (t < 1536) {
      float a = bih[t];  // + (Wih @ bd) fold of the dense bias
      for (int f = 0; f < 128; ++f) a = fmaf(Wih[t * 128 + f], bd[f], a);
      if (t < 1024) a += bhh[t];
      v = a;
    } else if (t < 2048) {
      v = bhh[t - 512];
    } else {
      v = bd[t - 2048];
    }
    biasP[t] = v;
  }
  if (t < 256 * 32) flags[t] = 0;
}

// ---------------- main persistent kernel ----------------
// 16 groups x 32 rows; 16 members x 32 gate-cols; wave v = K-quarter [128v,128v+128)
__global__ __launch_bounds__(256, 1) void k_main(
    const float* __restrict__ h0, const f16* __restrict__ whiF,
    const f16* __restrict__ wloF, const float* __restrict__ biasP,
    f16* __restrict__ hhi, f16* __restrict__ hlo, int* __restrict__ flags,
    float* __restrict__ out) {
  extern __shared__ char dsm[];
  f16* sHi = (f16*)(dsm + LDS_HI);
  f16* sLo = (f16*)(dsm + LDS_LO);
  float* ex = (float*)(dsm + LDS_EX);
  float* yp = (float*)(dsm + LDS_YP);

  const int bid = blockIdx.x;
  const int g = bid & 15;   // group: rows [32g, 32g+32). blockIdx%8 -> same XCD per group.
  const int m = bid >> 4;   // member: gate-cols [32m, 32m+32) of each type
  const int tid = threadIdx.x;
  const int v = tid >> 6, lane = tid & 63, q = lane >> 4, n = lane & 15;

  // ---- weight fragments resident in registers (hi+lo, this member's cols, this wave's K) ----
  const half8* whiV = (const half8*)whiF;
  const half8* wloV = (const half8*)wloF;
  half8 w_hi[4][2][4], w_lo[4][2][4];  // [type][ntile][ks]
#pragma unroll
  for (int t = 0; t < 4; ++t)
#pragma unroll
    for (int nt = 0; nt < 2; ++nt)
#pragma unroll
      for (int ks = 0; ks < 4; ++ks) {
        const int idx = ((t * 32 + m * 2 + nt) * 16 + v * 4 + ks) * 64 + lane;
        w_hi[t][nt][ks] = whiV[idx];
        w_lo[t][nt][ks] = wloV[idx];
      }
  half8 w_y[4];
  if (m < 8) {
#pragma unroll
    for (int ks = 0; ks < 4; ++ks) w_y[ks] = whiV[((128 + m) * 16 + v * 4 + ks) * 64 + lane];
  }

  // ---- per-thread gate-phase roles: row rl, 4 consecutive cols at c0 ----
  const int rl = tid >> 3, c0 = (tid & 7) * 4;
  float bias[4][4];
#pragma unroll
  for (int t = 0; t < 4; ++t)
#pragma unroll
    for (int cc = 0; cc < 4; ++cc) bias[t][cc] = biasP[t * 512 + m * 32 + c0 + cc];
  float hreg[4];  // fp32 h for the z*h path (exact)
#pragma unroll
  for (int cc = 0; cc < 4; ++cc)
    hreg[cc] = h0[(size_t)(32 * g + rl) * 512 + m * 32 + c0 + cc];
  const int c2 = (tid & 7) * 2;  // y-reduce role: row rl, 2 cols at c2
  float by[2] = {0.f, 0.f};
  if (m < 8) {
    by[0] = biasP[2048 + m * 16 + c2];
    by[1] = biasP[2048 + m * 16 + c2 + 1];
  }

  int* myflag = flags + (g * 16 + m) * 32;
  int* gflags = flags + g * 16 * 32;
  const size_t rowbaseB = (size_t)(32 * g) * 1024;  // bytes into an h plane buffer

  for (int s = 1; s <= 513; ++s) {
    // ---- stage h_{s-1} hi/lo planes (pre-swizzled in global) into LDS, async ----
    {
      const char* srcHi = (const char*)hhi + (size_t)((s - 1) & 1) * 524288 + rowbaseB;
      const char* srcLo = (const char*)hlo + (size_t)((s - 1) & 1) * 524288 + rowbaseB;
      const int off = v * 8192 + lane * 16;
#pragma unroll
      for (int i = 0; i < 8; ++i) {
        async16(srcHi + off + i * 1024, dsm + LDS_HI + off + i * 1024);
        async16(srcLo + off + i * 1024, dsm + LDS_LO + off + i * 1024);
      }
    }
    __syncthreads();  // waits vmcnt(0): async copies landed

    // ---- GEMM: 2 passes of 2 types; 3-term double-f16 (~fp32 accurate) ----
    float4v yac[2];
    if (m < 8) { yac[0] = (float4v){0,0,0,0}; yac[1] = (float4v){0,0,0,0}; }
#pragma unroll
    for (int p = 0; p < 2; ++p) {
      float4v a_hh[2][2][2], a_ll[2][2][2];  // [ti][nt][mt]
#pragma unroll
      for (int ti = 0; ti < 2; ++ti)
#pragma unroll
        for (int nt = 0; nt < 2; ++nt)
#pragma unroll
          for (int mt = 0; mt < 2; ++mt) {
            a_hh[ti][nt][mt] = (float4v){0,0,0,0};
            a_ll[ti][nt][mt] = (float4v){0,0,0,0};
          }
#pragma unroll
      for (int ks = 0; ks < 4; ++ks) {
        half8 ah[2], al[2];
#pragma unroll
        for (int mt = 0; mt < 2; ++mt) {
          const int offE = (mt * 16 + n) * 512 + ((((v * 4 + ks) * 4 + q) ^ (n & 7)) * 8);
          ah[mt] = *(const half8*)(sHi + offE);
          al[mt] = *(const half8*)(sLo + offE);
        }
#pragma unroll
        for (int ti = 0; ti < 2; ++ti) {
          const int t = p * 2 + ti;
#pragma unroll
          for (int nt = 0; nt < 2; ++nt)
#pragma unroll
            for (int mt = 0; mt < 2; ++mt) {
              a_hh[ti][nt][mt] = MFMA16(ah[mt], w_hi[t][nt][ks], a_hh[ti][nt][mt]);
              a_ll[ti][nt][mt] = MFMA16(al[mt], w_hi[t][nt][ks], a_ll[ti][nt][mt]);
              a_ll[ti][nt][mt] = MFMA16(ah[mt], w_lo[t][nt][ks], a_ll[ti][nt][mt]);
            }
        }
        if (p == 0 && m < 8) {
          yac[0] = MFMA16(ah[0], w_y[ks], yac[0]);
          yac[1] = MFMA16(ah[1], w_y[ks], yac[1]);
        }
      }
      // exchange writes for this pass (pass-0 writes hide under pass-1 MFMAs)
#pragma unroll
      for (int ti = 0; ti < 2; ++ti) {
        const int t = p * 2 + ti;
#pragma unroll
        for (int nt = 0; nt < 2; ++nt)
#pragma unroll
          for (int mt = 0; mt < 2; ++mt) {
            const int base = ((t * 4 + v) * 32 + nt * 16 + n) * EXS + mt * 16 + q * 4;
            const float4v vv = a_hh[ti][nt][mt] + a_ll[ti][nt][mt] * LO_R;
            *(float2v*)(ex + base) = (float2v){vv[0], vv[1]};
            *(float2v*)(ex + base + 2) = (float2v){vv[2], vv[3]};
          }
      }
      if (p == 0 && m < 8) {
#pragma unroll
        for (int mt = 0; mt < 2; ++mt)
#pragma unroll
          for (int e = 0; e < 4; ++e)
            yp[(v * 32 + mt * 16 + q * 4 + e) * 17 + n] = yac[mt][e];
      }
    }
    __syncthreads();

    // ---- reduce 4 K-quarter partials + bias, gate in fp32 ----
    float pre[4][4];
#pragma unroll
    for (int t = 0; t < 4; ++t)
#pragma unroll
      for (int cc = 0; cc < 4; ++cc) {
        float acc = bias[t][cc];
#pragma unroll
        for (int w = 0; w < 4; ++w) acc += ex[((t * 4 + w) * 32 + c0 + cc) * EXS + rl];
        pre[t][cc] = acc;
      }
    const int rg = 32 * g + rl;
    half4 hiv, lov;
#pragma unroll
    for (int cc = 0; cc < 4; ++cc) {
      const float r = sigm(pre[0][cc]);
      const float z = sigm(pre[1][cc]);
      const float nn = tanh_(fmaf(r, pre[3][cc], pre[2][cc]));
      const float hn = fmaf(z, hreg[cc] - nn, nn);  // (1-z)*n + z*h
      hreg[cc] = hn;
      const f16 hi = (f16)hn;
      hiv[cc] = hi;
      lov[cc] = (f16)((hn - (float)hi) * LO_S);
    }
    {
      const int colp = swz(m * 32 + c0, rg);
      const size_t o = (size_t)(s & 1) * 262144 + (size_t)rg * 512 + colp;
      *(half4*)(hhi + o) = hiv;
      *(half4*)(hlo + o) = lov;
    }
    __threadfence();
    __syncthreads();
    if (tid == 0) __hip_atomic_store(myflag, s, __ATOMIC_RELEASE, __HIP_MEMORY_SCOPE_AGENT);

    // ---- y_{s-1} = dense(h_{s-1}) -> out[:, s-2, :]  (during others' poll window) ----
    if (m < 8 && s >= 2) {
#pragma unroll
      for (int cc = 0; cc < 2; ++cc) {
        float yv = by[cc];
#pragma unroll
        for (int w = 0; w < 4; ++w) yv += yp[(w * 32 + rl) * 17 + c2 + cc];
        __builtin_nontemporal_store(
            yv, out + (size_t)rg * (Tsz * Fsz) + (size_t)(s - 2) * Fsz + m * 16 + c2 + cc);
      }
    }

    if (s < 513) {  // group barrier: 16 members, agent-scope flags
      if (v == 0 && lane < 16) {
        int* fl = gflags + lane * 32;
        while (__hip_atomic_load(fl, __ATOMIC_ACQUIRE, __HIP_MEMORY_SCOPE_AGENT) < s) {}
      }
      __syncthreads();
      __threadfence();  // acquire side: invalidate L1 before next stage
    }
  }
}

extern "C" void kernel_launch(void* const* d_in, const int* in_sizes, int n_in,
                              void* d_out, int out_size, void* d_ws, size_t ws_size,
                              hipStream_t stream) {
  (void)in_sizes; (void)n_in; (void)out_size; (void)ws_size;
  const float* h0  = (const float*)d_in[1];
  const float* Wih = (const float*)d_in[2];
  const float* Whh = (const float*)d_in[3];
  const float* bih = (const float*)d_in[4];
  const float* bhh = (const float*)d_in[5];
  const float* Wd  = (const float*)d_in[6];
  const float* bd  = (const float*)d_in[7];
  float* out = (float*)d_out;
  char* ws = (char*)d_ws;

  f16* whiF    = (f16*)(ws + OFF_WHI);
  f16* wloF    = (f16*)(ws + OFF_WLO);
  float* biasP = (float*)(ws + OFF_BIAS);
  f16* hhi     = (f16*)(ws + OFF_HHI);
  f16* hlo     = (f16*)(ws + OFF_HLO);
  int* flags   = (int*)(ws + OFF_FLAGS);

  hipFuncSetAttribute((const void*)k_main, hipFuncAttributeMaxDynamicSharedMemorySize,
                      LDS_TOT);
  k_pack<<<dim3(2, NPACK), 256, 0, stream>>>(Wih, Whh, Wd, whiF, wloF);
  k_init<<<1024, 256, 0, stream>>>(h0, Wih, bih, bhh, bd, hhi, hlo, biasP, flags);
  k_main<<<256, 256, LDS_TOT, stream>>>(h0, whiF, wloF, biasP, hhi, hlo, flags, out);
}

// Round 3
// 4604.068 us; speedup vs baseline: 5.4287x; 5.4287x over previous
//
#include <hip/hip_runtime.h>
#include <stdint.h>

typedef _Float16 f16;
typedef _Float16 half8 __attribute__((ext_vector_type(8)));
typedef _Float16 half4 __attribute__((ext_vector_type(4)));
typedef float float4v __attribute__((ext_vector_type(4)));
typedef float float2v __attribute__((ext_vector_type(2)));
typedef unsigned int u32;

#define MFMA16(A, B, C) __builtin_amdgcn_mfma_f32_16x16x32_f16((A), (B), (C), 0, 0, 0)

static constexpr int Bsz = 512, Tsz = 512, Fsz = 128, Lsz = 512;
static constexpr int NPACK = 2176;  // [r|z|in|hn] (4*512) + y (128)
static constexpr float LO_S = 2048.0f, LO_R = 1.0f / 2048.0f;

// ws layout (bytes)
static constexpr size_t WSZ_FRAG  = (size_t)(NPACK / 16) * 16 * 64 * 8 * 2;  // 2,228,224
static constexpr size_t OFF_WHI   = 0;
static constexpr size_t OFF_WLO   = OFF_WHI + WSZ_FRAG;
static constexpr size_t OFF_BIAS  = OFF_WLO + WSZ_FRAG;                  // 4,456,448
static constexpr size_t OFF_HHI   = OFF_BIAS + 16384;                    // 2 bufs x 512x512 f16
static constexpr size_t OFF_HLO   = OFF_HHI + (size_t)2 * Bsz * Lsz * 2;
static constexpr size_t OFF_FLAGS = OFF_HLO + (size_t)2 * Bsz * Lsz * 2; // 8192 ints

// LDS layout (bytes); dynamic
static constexpr int EXS = 37;          // odd stride: no even-bank aliasing
static constexpr int LDS_HI = 0;        // f16 [32][512] swizzled
static constexpr int LDS_LO = 32768;    // f16 [32][512] swizzled
static constexpr int LDS_EX = 65536;    // f32 [4t][4w][32col][EXS]
static constexpr int LDS_YP = LDS_EX + 16 * 32 * EXS * 4;  // f32 [4w][32row][17]
static constexpr int LDS_TOT = LDS_YP + 4 * 32 * 17 * 4;   // 150,016

// XOR swizzle of a column within a 512-col row (granule = 8 f16 = 16 B)
__device__ __host__ __forceinline__ int swz(int c, int r) {
  return (((c >> 3) ^ (r & 7)) << 3) | (c & 7);
}

// async global->LDS, 16B/lane, sc1 (device scope: bypass L1/L2, read at L3)
__device__ __forceinline__ void async16(const void* g, void* l) {
  __builtin_amdgcn_global_load_lds((const __attribute__((address_space(1))) u32*)g,
                                   (__attribute__((address_space(3))) u32*)l, 16, 0, 16);
}

__device__ __forceinline__ float sigm(float x) { return 1.0f / (1.0f + __expf(-x)); }
__device__ __forceinline__ float tanh_(float x) { return 1.0f - 2.0f / (__expf(2.0f * x) + 1.0f); }

// ---------------- prep kernel 1: fold + split + fragment-pack weights ----------------
// packed col c: [0,1024): r/z combined = M[l][c] + Whh[c][l]
//               [1024,1536): i_n       = M[l][c]
//               [1536,2048): h_n       = Whh[c-512][l]
//               [2048,2176): y         = Wd[c-2048][l]
// where M[l][j] = sum_f Wd[f][l] * Wih[j][f]  (dense layer folded into input weights)
__global__ void k_pack(const float* __restrict__ Wih, const float* __restrict__ Whh,
                       const float* __restrict__ Wd, f16* __restrict__ whiF,
                       f16* __restrict__ wloF) {
  const int c = blockIdx.y;                      // 0..2175 (uniform per block)
  const int l = blockIdx.x * 256 + threadIdx.x;  // 0..511 (contraction index)
  float v;
  if (c < 1536) {
    const float* wih = Wih + c * 128;
    float acc = 0.f;
#pragma unroll 8
    for (int f = 0; f < 128; ++f) acc = fmaf(Wd[f * 512 + l], wih[f], acc);
    v = acc;
    if (c < 1024) v += Whh[c * 512 + l];
  } else if (c < 2048) {
    v = Whh[(c - 512) * 512 + l];
  } else {
    v = Wd[(c - 2048) * 512 + l];
  }
  f16 hi = (f16)v;
  f16 lo = (f16)((v - (float)hi) * LO_S);  // scaled: raw residual is fp16-subnormal
  // B-fragment layout for mfma 16x16x32: lane=q*16+n holds B[k=32*ks+8*q+j][n]
  const int chunk = c >> 4, ks = l >> 5, q = (l >> 3) & 3, j = l & 7, n = c & 15;
  const size_t idx = (((size_t)(chunk * 16 + ks)) * 64 + q * 16 + n) * 8 + j;
  whiF[idx] = hi;
  wloF[idx] = lo;
}

// ---------------- prep kernel 2: h planes (buffer 0), biases, flags ----------------
__global__ void k_init(const float* __restrict__ h0, const float* __restrict__ Wih,
                       const float* __restrict__ bih, const float* __restrict__ bhh,
                       const float* __restrict__ bd, f16* __restrict__ hhi,
                       f16* __restrict__ hlo, float* __restrict__ biasP,
                       int* __restrict__ flags) {
  const int t = blockIdx.x * 256 + threadIdx.x;
  if (t < Bsz * Lsz) {
    const int row = t >> 9, col = t & 511;
    float v = h0[t];
    f16 hi = (f16)v;
    f16 lo = (f16)((v - (float)hi) * LO_S);
    const int cp = swz(col, row);
    hhi[row * 512 + cp] = hi;  // buffer 0 (kernel-end implicit release flushes to L3)
    hlo[row * 512 + cp] = lo;
  }
  if (t < NPACK) {
    float v;
    if (t < 1536) {
      float a = bih[t];  // + (Wih @ bd) fold of the dense bias
      for (int f = 0; f < 128; ++f) a = fmaf(Wih[t * 128 + f], bd[f], a);
      if (t < 1024) a += bhh[t];
      v = a;
    } else if (t < 2048) {
      v = bhh[t - 512];
    } else {
      v = bd[t - 2048];
    }
    biasP[t] = v;
  }
  if (t < 8192) flags[t] = 0;
}

// ---------------- main persistent kernel ----------------
// 16 groups x 32 rows; 16 members x 32 gate-cols; wave v = K-quarter [128v,128v+128)
// All cross-CU h traffic rides through L3 (sc1 stores / sc1 loads) — no cache fences.
__global__ __launch_bounds__(256, 1) void k_main(
    const float* __restrict__ h0, const f16* __restrict__ whiF,
    const f16* __restrict__ wloF, const float* __restrict__ biasP,
    f16* __restrict__ hhi, f16* __restrict__ hlo, int* __restrict__ flags,
    float* __restrict__ out) {
  extern __shared__ char dsm[];
  f16* sHi = (f16*)(dsm + LDS_HI);
  f16* sLo = (f16*)(dsm + LDS_LO);
  float* ex = (float*)(dsm + LDS_EX);
  float* yp = (float*)(dsm + LDS_YP);

  const int bid = blockIdx.x;
  const int g = bid & 15;   // group: rows [32g, 32g+32)
  const int m = bid >> 4;   // member: gate-cols [32m, 32m+32) of each type
  const int tid = threadIdx.x;
  const int v = tid >> 6, lane = tid & 63, q = lane >> 4, n = lane & 15;

  // ---- weight fragments resident in registers (hi+lo, this member's cols, this wave's K) ----
  const half8* whiV = (const half8*)whiF;
  const half8* wloV = (const half8*)wloF;
  half8 w_hi[4][2][4], w_lo[4][2][4];  // [type][ntile][ks]
#pragma unroll
  for (int t = 0; t < 4; ++t)
#pragma unroll
    for (int nt = 0; nt < 2; ++nt)
#pragma unroll
      for (int ks = 0; ks < 4; ++ks) {
        const int idx = ((t * 32 + m * 2 + nt) * 16 + v * 4 + ks) * 64 + lane;
        w_hi[t][nt][ks] = whiV[idx];
        w_lo[t][nt][ks] = wloV[idx];
      }
  half8 w_y[4];
  if (m < 8) {
#pragma unroll
    for (int ks = 0; ks < 4; ++ks) w_y[ks] = whiV[((128 + m) * 16 + v * 4 + ks) * 64 + lane];
  }

  // ---- per-thread gate-phase roles: row rl, 4 consecutive cols at c0 ----
  const int rl = tid >> 3, c0 = (tid & 7) * 4;
  float bias[4][4];
#pragma unroll
  for (int t = 0; t < 4; ++t)
#pragma unroll
    for (int cc = 0; cc < 4; ++cc) bias[t][cc] = biasP[t * 512 + m * 32 + c0 + cc];
  float hreg[4];  // fp32 h for the z*h path (exact)
#pragma unroll
  for (int cc = 0; cc < 4; ++cc)
    hreg[cc] = h0[(size_t)(32 * g + rl) * 512 + m * 32 + c0 + cc];
  const int c2 = (tid & 7) * 2;  // y-reduce role: row rl, 2 cols at c2
  float by[2] = {0.f, 0.f};
  if (m < 8) {
    by[0] = biasP[2048 + m * 16 + c2];
    by[1] = biasP[2048 + m * 16 + c2 + 1];
  }

  int* gcnt = flags + g * 64;  // one counter per group, 256B apart
  const size_t rowbaseB = (size_t)(32 * g) * 1024;  // bytes into an h plane buffer

  for (int s = 1; s <= 513; ++s) {
    // ---- stage h_{s-1} hi/lo planes from L3 into LDS, async sc1 ----
    {
      const char* srcHi = (const char*)hhi + (size_t)((s - 1) & 1) * 524288 + rowbaseB;
      const char* srcLo = (const char*)hlo + (size_t)((s - 1) & 1) * 524288 + rowbaseB;
      const int off = v * 8192 + lane * 16;
#pragma unroll
      for (int i = 0; i < 8; ++i) {
        async16(srcHi + off + i * 1024, dsm + LDS_HI + off + i * 1024);
        async16(srcLo + off + i * 1024, dsm + LDS_LO + off + i * 1024);
      }
    }
    __syncthreads();  // drains vmcnt: async copies landed

    // ---- GEMM: 2 passes of 2 types; 3-term double-f16 (~fp32 accurate) ----
    float4v yac[2];
    if (m < 8) { yac[0] = (float4v){0,0,0,0}; yac[1] = (float4v){0,0,0,0}; }
#pragma unroll
    for (int p = 0; p < 2; ++p) {
      float4v a_hh[2][2][2], a_ll[2][2][2];  // [ti][nt][mt]
#pragma unroll
      for (int ti = 0; ti < 2; ++ti)
#pragma unroll
        for (int nt = 0; nt < 2; ++nt)
#pragma unroll
          for (int mt = 0; mt < 2; ++mt) {
            a_hh[ti][nt][mt] = (float4v){0,0,0,0};
            a_ll[ti][nt][mt] = (float4v){0,0,0,0};
          }
#pragma unroll
      for (int ks = 0; ks < 4; ++ks) {
        half8 ah[2], al[2];
#pragma unroll
        for (int mt = 0; mt < 2; ++mt) {
          const int offE = (mt * 16 + n) * 512 + ((((v * 4 + ks) * 4 + q) ^ (n & 7)) * 8);
          ah[mt] = *(const half8*)(sHi + offE);
          al[mt] = *(const half8*)(sLo + offE);
        }
#pragma unroll
        for (int ti = 0; ti < 2; ++ti) {
          const int t = p * 2 + ti;
#pragma unroll
          for (int nt = 0; nt < 2; ++nt)
#pragma unroll
            for (int mt = 0; mt < 2; ++mt) {
              a_hh[ti][nt][mt] = MFMA16(ah[mt], w_hi[t][nt][ks], a_hh[ti][nt][mt]);
              a_ll[ti][nt][mt] = MFMA16(al[mt], w_hi[t][nt][ks], a_ll[ti][nt][mt]);
              a_ll[ti][nt][mt] = MFMA16(ah[mt], w_lo[t][nt][ks], a_ll[ti][nt][mt]);
            }
        }
        if (p == 0 && m < 8) {
          yac[0] = MFMA16(ah[0], w_y[ks], yac[0]);
          yac[1] = MFMA16(ah[1], w_y[ks], yac[1]);
        }
      }
      // exchange writes for this pass (pass-0 writes hide under pass-1 MFMAs)
#pragma unroll
      for (int ti = 0; ti < 2; ++ti) {
        const int t = p * 2 + ti;
#pragma unroll
        for (int nt = 0; nt < 2; ++nt)
#pragma unroll
          for (int mt = 0; mt < 2; ++mt) {
            const int base = ((t * 4 + v) * 32 + nt * 16 + n) * EXS + mt * 16 + q * 4;
            const float4v vv = a_hh[ti][nt][mt] + a_ll[ti][nt][mt] * LO_R;
            *(float2v*)(ex + base) = (float2v){vv[0], vv[1]};
            *(float2v*)(ex + base + 2) = (float2v){vv[2], vv[3]};
          }
      }
      if (p == 0 && m < 8) {
#pragma unroll
        for (int mt = 0; mt < 2; ++mt)
#pragma unroll
          for (int e = 0; e < 4; ++e)
            yp[(v * 32 + mt * 16 + q * 4 + e) * 17 + n] = yac[mt][e];
      }
    }
    __syncthreads();

    // ---- reduce 4 K-quarter partials + bias, gate in fp32 ----
    float pre[4][4];
#pragma unroll
    for (int t = 0; t < 4; ++t)
#pragma unroll
      for (int cc = 0; cc < 4; ++cc) {
        float acc = bias[t][cc];
#pragma unroll
        for (int w = 0; w < 4; ++w) acc += ex[((t * 4 + w) * 32 + c0 + cc) * EXS + rl];
        pre[t][cc] = acc;
      }
    const int rg = 32 * g + rl;
    half4 hiv, lov;
#pragma unroll
    for (int cc = 0; cc < 4; ++cc) {
      const float r = sigm(pre[0][cc]);
      const float z = sigm(pre[1][cc]);
      const float nn = tanh_(fmaf(r, pre[3][cc], pre[2][cc]));
      const float hn = fmaf(z, hreg[cc] - nn, nn);  // (1-z)*n + z*h
      hreg[cc] = hn;
      const f16 hi = (f16)hn;
      hiv[cc] = hi;
      lov[cc] = (f16)((hn - (float)hi) * LO_S);
    }
    {
      // write-through (sc1) 8B atomic stores: h lands at the L3 coherence point
      const int colp = swz(m * 32 + c0, rg);
      const size_t o = (size_t)(s & 1) * 262144 + (size_t)rg * 512 + colp;
      __hip_atomic_store((uint64_t*)(hhi + o), __builtin_bit_cast(uint64_t, hiv),
                         __ATOMIC_RELAXED, __HIP_MEMORY_SCOPE_AGENT);
      __hip_atomic_store((uint64_t*)(hlo + o), __builtin_bit_cast(uint64_t, lov),
                         __ATOMIC_RELAXED, __HIP_MEMORY_SCOPE_AGENT);
    }
    asm volatile("s_waitcnt vmcnt(0)" ::: "memory");  // h stores acked at L3
    __syncthreads();                                  // ... for all 4 waves
    if (tid == 0)
      __hip_atomic_fetch_add(gcnt, 1, __ATOMIC_RELAXED, __HIP_MEMORY_SCOPE_AGENT);

    // ---- y_{s-1} = dense(h_{s-1}) -> out[:, s-2, :]  (during others' poll window) ----
    if (m < 8 && s >= 2) {
#pragma unroll
      for (int cc = 0; cc < 2; ++cc) {
        float yv = by[cc];
#pragma unroll
        for (int w = 0; w < 4; ++w) yv += yp[(w * 32 + rl) * 17 + c2 + cc];
        __builtin_nontemporal_store(
            yv, out + (size_t)rg * (Tsz * Fsz) + (size_t)(s - 2) * Fsz + m * 16 + c2 + cc);
      }
    }

    if (s < 513) {  // group barrier: single counter, relaxed polls (no fences)
      if (tid == 0) {
        while (__hip_atomic_load(gcnt, __ATOMIC_RELAXED, __HIP_MEMORY_SCOPE_AGENT) <
               16 * s)
          __builtin_amdgcn_s_sleep(2);
      }
      __syncthreads();
    }
  }
}

extern "C" void kernel_launch(void* const* d_in, const int* in_sizes, int n_in,
                              void* d_out, int out_size, void* d_ws, size_t ws_size,
                              hipStream_t stream) {
  (void)in_sizes; (void)n_in; (void)out_size; (void)ws_size;
  const float* h0  = (const float*)d_in[1];
  const float* Wih = (const float*)d_in[2];
  const float* Whh = (const float*)d_in[3];
  const float* bih = (const float*)d_in[4];
  const float* bhh = (const float*)d_in[5];
  const float* Wd  = (const float*)d_in[6];
  const float* bd  = (const float*)d_in[7];
  float* out = (float*)d_out;
  char* ws = (char*)d_ws;

  f16* whiF    = (f16*)(ws + OFF_WHI);
  f16* wloF    = (f16*)(ws + OFF_WLO);
  float* biasP = (float*)(ws + OFF_BIAS);
  f16* hhi     = (f16*)(ws + OFF_HHI);
  f16* hlo     = (f16*)(ws + OFF_HLO);
  int* flags   = (int*)(ws + OFF_FLAGS);

  hipFuncSetAttribute((const void*)k_main, hipFuncAttributeMaxDynamicSharedMemorySize,
                      LDS_TOT);
  k_pack<<<dim3(2, NPACK), 256, 0, stream>>>(Wih, Whh, Wd, whiF, wloF);
  k_init<<<1024, 256, 0, stream>>>(h0, Wih, bih, bhh, bd, hhi, hlo, biasP, flags);
  k_main<<<256, 256, LDS_TOT, stream>>>(h0, whiF, wloF, biasP, hhi, hlo, flags, out);
}